// Round 15
// baseline (383.331 us; speedup 1.0000x reference)
//
#include <hip/hip_runtime.h>

#define D1 512
#define K2 128

typedef __bf16 bf16_t;
typedef bf16_t bf16x8 __attribute__((ext_vector_type(8)));
typedef bf16_t bf16x4 __attribute__((ext_vector_type(4)));
typedef float  f32x4  __attribute__((ext_vector_type(4)));
typedef float  f32x16 __attribute__((ext_vector_type(16)));

#define WBF_OFF 0ull
#define XBF_OFF 67108864ull
#define WS_NEED 71303168ull

// ---------------- prep W: fp32 [k][i][j] -> Wbf bf16 A-frag stream ----------------
// Wbf[k][is(16)][s(32)][l(64)][e(8)]: lane l of a wave loads 16B = W[k][is*32+(l&31)][s*16+(l>>5)*8+e]
__global__ __launch_bounds__(256)
void prep_w(const float* __restrict__ W, bf16_t* __restrict__ Wbf)
{
    const int k  = blockIdx.x >> 4;
    const int is = blockIdx.x & 15;
    const int t  = threadIdx.x;
    __shared__ float lt[16384];            // 32 rows x 2048 B, 16B-slot XOR swizzle
    char* ltb = (char*)lt;
    {
        const int r  = t >> 3;
        const int cb = (t & 7) * 64;
        const float* src = W + ((size_t)k * D1 + is * 32 + r) * D1 + cb;
        const int sw = (r & 15) << 4;
        #pragma unroll
        for (int c = 0; c < 16; ++c) {
            float4 v = *reinterpret_cast<const float4*>(src + c * 4);
            *reinterpret_cast<float4*>(ltb + r * 2048 + (((cb + c * 4) * 4) ^ sw)) = v;
        }
    }
    __syncthreads();
    bf16_t* out = Wbf + ((size_t)k * 16 + is) * 16384;
    #pragma unroll
    for (int p = 0; p < 8; ++p) {
        const int cc = p * 256 + t;        // 0..2047 = s*64 + l
        const int s  = cc >> 6;
        const int l2 = cc & 63;
        const int il = l2 & 31;
        const int jb = s * 16 + (l2 >> 5) * 8;
        const int sw = (il & 15) << 4;
        bf16x8 h;
        #pragma unroll
        for (int e = 0; e < 8; ++e) {
            float v = *reinterpret_cast<const float*>(ltb + il * 2048 + (((jb + e) * 4) ^ sw));
            h[e] = (bf16_t)v;
        }
        *reinterpret_cast<bf16x8*>(out + (size_t)cc * 8) = h;
    }
}

// ---------------- prep X: fp32 [n][d] -> Xbf (B-frag LDS image, pre-swizzled)
// Xbf[nb2(32)][jc(4)][chunk(2048)][e(8)]: chunk = n*16+slot, content = X[nb2*128+n][jc*128+(slot^(n&15))*8+e]
__global__ __launch_bounds__(256)
void prep_x(const float* __restrict__ X, bf16_t* __restrict__ Xbf)
{
    const int nb2 = blockIdx.x >> 2;
    const int jc  = blockIdx.x & 3;
    const int t   = threadIdx.x;
    __shared__ float xt[16384];            // [128 n][128 j]
    {
        const int nl = t >> 1;
        const int cb = (t & 1) * 64;
        const float* src = X + ((size_t)nb2 * 128 + nl) * D1 + jc * 128 + cb;
        #pragma unroll
        for (int c = 0; c < 16; ++c) {
            float4 v = *reinterpret_cast<const float4*>(src + c * 4);
            *reinterpret_cast<float4*>(&xt[nl * 128 + cb + c * 4]) = v;
        }
    }
    __syncthreads();
    bf16_t* outx = Xbf + ((size_t)nb2 * 4 + jc) * 16384;
    #pragma unroll
    for (int p = 0; p < 8; ++p) {
        const int cc   = p * 256 + t;
        const int n    = cc >> 4;
        const int slot = cc & 15;
        const int j8   = slot ^ (n & 15);
        bf16x8 h;
        #pragma unroll
        for (int e = 0; e < 8; ++e) h[e] = (bf16_t)xt[n * 128 + j8 * 8 + e];
        *reinterpret_cast<bf16x8*>(outx + (size_t)cc * 8) = h;
    }
}

// ---------------- main: W-as-A, X-as-B. Block = (k, 64-row n-tile), 8 waves.
// R13's proven structure (wave = 64i x 64n, acc[2][2] = 64 AGPR, 4 waves/SIMD,
// 2 blocks/CU, 66 KB LDS). Single change vs R13: bid mapping k=bid&127,
// nt=bid>>7 -> co-resident CU pairs (delta-bid ~256) share the SAME k with
// adjacent n-tiles, so the second block's A-stream hits L1 -> per-CU L2
// A-traffic halves (62 -> ~31 B/cyc, under the ~60 B/cyc ceiling).
__global__ __launch_bounds__(512, 4)
void tr_main(const bf16_t* __restrict__ Wbf, const bf16_t* __restrict__ Xbf,
             float* __restrict__ Y)
{
    extern __shared__ char smem[];         // 4 x 16 KB X half-tiles + 2 KB reduce
    float* red = (float*)(smem + 65536);

    const int bid = blockIdx.x;
    const int k   = bid & 127;             // same-XCD => same k mod 8; pairs share k
    const int nb  = bid >> 7;              // 64-row n-tile 0..63

    const int tid = threadIdx.x;
    const int w   = tid >> 6;
    const int l   = tid & 63;
    const int l31 = l & 31;
    const int lh  = l >> 5;

    // stage 4 X half-tiles (16 KB each) from the pre-swizzled image, reg-staged
    {
        const bf16_t* src = Xbf + (size_t)(nb >> 1) * 65536 + (size_t)(nb & 1) * 8192;
        bf16x8 tmp[8];
        #pragma unroll
        for (int jc = 0; jc < 4; ++jc)
            #pragma unroll
            for (int p = 0; p < 2; ++p) {
                const int ci = p * 512 + tid;        // 0..1023
                tmp[jc * 2 + p] = *reinterpret_cast<const bf16x8*>(
                    src + (size_t)jc * 16384 + (size_t)ci * 8);
            }
        #pragma unroll
        for (int jc = 0; jc < 4; ++jc)
            #pragma unroll
            for (int p = 0; p < 2; ++p) {
                const int ci = p * 512 + tid;
                *reinterpret_cast<bf16x8*>(smem + jc * 16384 + ci * 16) = tmp[jc * 2 + p];
            }
    }
    __syncthreads();

    // A-frag stream: strip mi at A0 + mi*16384 (wave w owns i in [w*64, w*64+64))
    const bf16_t* A0 = Wbf + ((size_t)k * 16 + w * 2) * 16384 + (size_t)l * 8;
    const int sw = (l & 15) << 4;

    f32x16 acc[2][2] = {};

    // depth-2 A-prefetch queue (statically indexed under full unroll)
    bf16x8 Aq[2][2];
    #pragma unroll
    for (int d = 0; d < 2; ++d) {
        Aq[d][0] = *reinterpret_cast<const bf16x8*>(A0 + (size_t)d * 512);
        Aq[d][1] = *reinterpret_cast<const bf16x8*>(A0 + 16384 + (size_t)d * 512);
    }

    auto bread = [&](bf16x8* dst, int su) { // su = j-chunk index 0..31
        const char* base = smem + (su >> 3) * 16384;
        const int ct = ((((su & 7) * 2 + lh) << 4)) ^ sw;
        #pragma unroll
        for (int fn = 0; fn < 2; ++fn)
            dst[fn] = *reinterpret_cast<const bf16x8*>(
                base + (fn * 32 + l31) * 256 + ct);
    };

    // B double-buffer, 2-step-ahead: slot qi is refilled for s+2 right after
    // step s's burst consumes it. Prologue fills steps 0 and 1.
    bf16x8 B[2][2];
    bread(B[0], 0);
    bread(B[1], 1);

    #pragma unroll
    for (int s = 0; s < 32; ++s) {
        const int qi = s & 1;
        bf16x8 a0 = Aq[qi][0];
        bf16x8 a1 = Aq[qi][1];
        if (s + 2 < 32) {                  // A prefetch, 2 steps ahead (L2/L1-resident)
            Aq[qi][0] = *reinterpret_cast<const bf16x8*>(A0 + (size_t)(s + 2) * 512);
            Aq[qi][1] = *reinterpret_cast<const bf16x8*>(A0 + 16384 + (size_t)(s + 2) * 512);
        }
        __builtin_amdgcn_s_setprio(1);
        acc[0][0] = __builtin_amdgcn_mfma_f32_32x32x16_bf16(a0, B[qi][0], acc[0][0], 0, 0, 0);
        acc[0][1] = __builtin_amdgcn_mfma_f32_32x32x16_bf16(a0, B[qi][1], acc[0][1], 0, 0, 0);
        acc[1][0] = __builtin_amdgcn_mfma_f32_32x32x16_bf16(a1, B[qi][0], acc[1][0], 0, 0, 0);
        acc[1][1] = __builtin_amdgcn_mfma_f32_32x32x16_bf16(a1, B[qi][1], acc[1][1], 0, 0, 0);
        __builtin_amdgcn_s_setprio(0);
        __builtin_amdgcn_sched_barrier(0);  // pin the refill BELOW the burst
        if (s + 2 < 32) bread(B[qi], s + 2);   // refill consumed slot, 2 ahead
    }

    // epilogue: yp[n] = sum_i acc[i,n] * X[n,i], X from the resident LDS tiles.
    // C/D: col(n)=l&31, row(i)=st32*32+(r&3)+8*(r>>2)+4*lh; i-quads 4-consecutive.
    float yp[2] = {0.f, 0.f};
    #pragma unroll
    for (int mi = 0; mi < 2; ++mi) {
        const int st32 = w * 2 + mi;
        const char* base = smem + (st32 >> 2) * 16384;
        #pragma unroll
        for (int rq = 0; rq < 4; ++rq) {
            const int slot = (st32 * 4 + rq) & 15;
            #pragma unroll
            for (int fn = 0; fn < 2; ++fn) {
                const int n = fn * 32 + l31;
                bf16x4 xv = *reinterpret_cast<const bf16x4*>(
                    base + n * 256 + ((slot ^ (n & 15)) << 4) + lh * 8);
                #pragma unroll
                for (int q = 0; q < 4; ++q)
                    yp[fn] += acc[mi][fn][rq * 4 + q] * (float)xv[q];
            }
        }
    }
    #pragma unroll
    for (int fn = 0; fn < 2; ++fn) {
        float v = yp[fn];
        v += __shfl_down(v, 32);
        if (lh == 0) red[w * 64 + fn * 32 + l31] = v;
    }
    __syncthreads();
    if (tid < 64) {
        float s2 = 0.f;
        #pragma unroll
        for (int w2 = 0; w2 < 8; ++w2) s2 += red[w2 * 64 + tid];
        Y[((size_t)nb * 64 + tid) * K2 + k] = s2;
    }
}

// ---------------- fallback (R1, proven 458 us, no ws) ----------------
__global__ __launch_bounds__(512, 2)
void tensor_reduction_kernel(const float* __restrict__ X,
                             const float* __restrict__ W,
                             float* __restrict__ Y)
{
    const int bid = blockIdx.x;
    const int xcd = bid & 7;
    const int rr_ = bid >> 3;
    const int kk  = xcd + 8 * (rr_ >> 4);
    const int nb  = (rr_ & 15) * 256;

    const int tid = threadIdx.x;
    const int wv  = tid >> 6;
    const int ln  = tid & 63;
    const int lg  = ln >> 4;
    const int lr  = ln & 15;

    __shared__ __align__(16) bf16_t Xs[256 * 64];
    __shared__ __align__(16) bf16_t Ws[2][64 * 64];

    bf16x8 afrag[2][16];
    {
        const int srow = tid >> 4;
        const int sj4  = (tid & 15) * 4;
        #pragma unroll
        for (int c = 0; c < 8; ++c) {
            #pragma unroll
            for (int p = 0; p < 8; ++p) {
                const int row = p * 32 + srow;
                float4 v = *reinterpret_cast<const float4*>(
                    X + (size_t)(nb + row) * D1 + c * 64 + sj4);
                bf16x4 h = { (bf16_t)v.x, (bf16_t)v.y, (bf16_t)v.z, (bf16_t)v.w };
                const int byte = row * 128 + ((sj4 * 2) ^ ((row & 7) << 4));
                *reinterpret_cast<bf16x4*>((char*)Xs + byte) = h;
            }
            __syncthreads();
            #pragma unroll
            for (int m = 0; m < 2; ++m) {
                #pragma unroll
                for (int ks = 0; ks < 2; ++ks) {
                    const int row  = wv * 32 + m * 16 + lr;
                    const int byte = row * 128 + ((ks * 64 + lg * 16) ^ ((row & 7) << 4));
                    afrag[m][2 * c + ks] =
                        *reinterpret_cast<const bf16x8*>((const char*)Xs + byte);
                }
            }
            __syncthreads();
        }
    }

    const float* Wk  = W + (size_t)kk * D1 * D1;
    const int irow = tid >> 3;
    const int j8   = (tid & 7) * 8;

    float ypart[2][4] = {{0.f,0.f,0.f,0.f},{0.f,0.f,0.f,0.f}};

    {
        const float* src = Wk + (size_t)irow * D1 + j8;
        float4 u0 = *reinterpret_cast<const float4*>(src);
        float4 u1 = *reinterpret_cast<const float4*>(src + 4);
        bf16x8 h = { (bf16_t)u0.x,(bf16_t)u0.y,(bf16_t)u0.z,(bf16_t)u0.w,
                     (bf16_t)u1.x,(bf16_t)u1.y,(bf16_t)u1.z,(bf16_t)u1.w };
        const int byte = irow * 128 + ((j8 * 2) ^ ((irow & 7) << 4));
        *reinterpret_cast<bf16x8*>((char*)Ws[0] + byte) = h;
    }
    __syncthreads();

    for (int it = 0; it < 8; ++it) {
        f32x4 acc[2][4] = {};
        #pragma unroll
        for (int jcc = 0; jcc < 8; ++jcc) {
            const int tI  = it * 8 + jcc;
            const int cur = tI & 1;
            float4 u0, u1;
            const bool pf = (tI < 63);
            if (pf) {
                const int nit = (tI + 1) >> 3, njc = (tI + 1) & 7;
                const float* src = Wk + (size_t)(nit * 64 + irow) * D1 + njc * 64 + j8;
                u0 = *reinterpret_cast<const float4*>(src);
                u1 = *reinterpret_cast<const float4*>(src + 4);
            }
            #pragma unroll
            for (int ks = 0; ks < 2; ++ks) {
                bf16x8 bfr[4];
                #pragma unroll
                for (int f = 0; f < 4; ++f) {
                    const int ir   = f * 16 + lr;
                    const int byte = ir * 128 + ((ks * 64 + lg * 16) ^ ((ir & 7) << 4));
                    bfr[f] = *reinterpret_cast<const bf16x8*>((const char*)Ws[cur] + byte);
                }
                #pragma unroll
                for (int m = 0; m < 2; ++m)
                    #pragma unroll
                    for (int f = 0; f < 4; ++f)
                        acc[m][f] = __builtin_amdgcn_mfma_f32_16x16x32_bf16(
                            afrag[m][2 * jcc + ks], bfr[f], acc[m][f], 0, 0, 0);
            }
            if (pf) {
                bf16x8 h = { (bf16_t)u0.x,(bf16_t)u0.y,(bf16_t)u0.z,(bf16_t)u0.w,
                             (bf16_t)u1.x,(bf16_t)u1.y,(bf16_t)u1.z,(bf16_t)u1.w };
                const int byte = irow * 128 + ((j8 * 2) ^ ((irow & 7) << 4));
                *reinterpret_cast<bf16x8*>((char*)Ws[cur ^ 1] + byte) = h;
            }
            __syncthreads();
        }
        #pragma unroll
        for (int m = 0; m < 2; ++m) {
            #pragma unroll
            for (int f = 0; f < 4; ++f) {
                const int col = it * 64 + f * 16 + lr;
                #pragma unroll
                for (int q = 0; q < 4; ++q) {
                    const int grow = nb + wv * 32 + m * 16 + lg * 4 + q;
                    ypart[m][q] += acc[m][f][q] * X[(size_t)grow * D1 + col];
                }
            }
        }
    }

    #pragma unroll
    for (int m = 0; m < 2; ++m) {
        #pragma unroll
        for (int q = 0; q < 4; ++q) {
            float v = ypart[m][q];
            v += __shfl_xor(v, 1, 64);
            v += __shfl_xor(v, 2, 64);
            v += __shfl_xor(v, 4, 64);
            v += __shfl_xor(v, 8, 64);
            if (lr == 0) {
                const int grow = nb + wv * 32 + m * 16 + lg * 4 + q;
                Y[(size_t)grow * K2 + kk] = v;
            }
        }
    }
}

extern "C" void kernel_launch(void* const* d_in, const int* in_sizes, int n_in,
                              void* d_out, int out_size, void* d_ws, size_t ws_size,
                              hipStream_t stream)
{
    const float* X = (const float*)d_in[0];   // [4096, 512] fp32
    const float* W = (const float*)d_in[1];   // [128, 512, 512] fp32
    float* Y = (float*)d_out;                 // [4096, 128] fp32

    if (d_ws != nullptr && ws_size >= WS_NEED) {
        bf16_t* Wbf = (bf16_t*)((char*)d_ws + WBF_OFF);
        bf16_t* Xbf = (bf16_t*)((char*)d_ws + XBF_OFF);
        prep_w<<<2048, 256, 0, stream>>>(W, Wbf);
        prep_x<<<128, 256, 0, stream>>>(X, Xbf);
        (void)hipFuncSetAttribute((const void*)tr_main,
                                  hipFuncAttributeMaxDynamicSharedMemorySize, 67584);
        tr_main<<<8192, 512, 67584, stream>>>(Wbf, Xbf, Y);
    } else {
        tensor_reduction_kernel<<<2048, 512, 0, stream>>>(X, W, Y);
    }
}

// Round 16
// 329.749 us; speedup vs baseline: 1.1625x; 1.1625x over previous
//
#include <hip/hip_runtime.h>

#define D1 512
#define K2 128

typedef __bf16 bf16_t;
typedef bf16_t bf16x8 __attribute__((ext_vector_type(8)));
typedef bf16_t bf16x4 __attribute__((ext_vector_type(4)));
typedef float  f32x4  __attribute__((ext_vector_type(4)));
typedef float  f32x16 __attribute__((ext_vector_type(16)));

#define WBF_OFF 0ull
#define XBF_OFF 67108864ull
#define WS_NEED 71303168ull

// ---------------- prep W: fp32 [k][i][j] -> Wbf bf16 A-frag stream ----------------
// Wbf[k][is(16)][s(32)][l(64)][e(8)]: lane l of a wave loads 16B = W[k][is*32+(l&31)][s*16+(l>>5)*8+e]
__global__ __launch_bounds__(256)
void prep_w(const float* __restrict__ W, bf16_t* __restrict__ Wbf)
{
    const int k  = blockIdx.x >> 4;
    const int is = blockIdx.x & 15;
    const int t  = threadIdx.x;
    __shared__ float lt[16384];            // 32 rows x 2048 B, 16B-slot XOR swizzle
    char* ltb = (char*)lt;
    {
        const int r  = t >> 3;
        const int cb = (t & 7) * 64;
        const float* src = W + ((size_t)k * D1 + is * 32 + r) * D1 + cb;
        const int sw = (r & 15) << 4;
        #pragma unroll
        for (int c = 0; c < 16; ++c) {
            float4 v = *reinterpret_cast<const float4*>(src + c * 4);
            *reinterpret_cast<float4*>(ltb + r * 2048 + (((cb + c * 4) * 4) ^ sw)) = v;
        }
    }
    __syncthreads();
    bf16_t* out = Wbf + ((size_t)k * 16 + is) * 16384;
    #pragma unroll
    for (int p = 0; p < 8; ++p) {
        const int cc = p * 256 + t;        // 0..2047 = s*64 + l
        const int s  = cc >> 6;
        const int l2 = cc & 63;
        const int il = l2 & 31;
        const int jb = s * 16 + (l2 >> 5) * 8;
        const int sw = (il & 15) << 4;
        bf16x8 h;
        #pragma unroll
        for (int e = 0; e < 8; ++e) {
            float v = *reinterpret_cast<const float*>(ltb + il * 2048 + (((jb + e) * 4) ^ sw));
            h[e] = (bf16_t)v;
        }
        *reinterpret_cast<bf16x8*>(out + (size_t)cc * 8) = h;
    }
}

// ---------------- prep X: fp32 [n][d] -> Xbf (B-frag LDS image, pre-swizzled)
// Xbf[nb2(32)][jc(4)][chunk(2048)][e(8)]: chunk = n*16+slot, content = X[nb2*128+n][jc*128+(slot^(n&15))*8+e]
__global__ __launch_bounds__(256)
void prep_x(const float* __restrict__ X, bf16_t* __restrict__ Xbf)
{
    const int nb2 = blockIdx.x >> 2;
    const int jc  = blockIdx.x & 3;
    const int t   = threadIdx.x;
    __shared__ float xt[16384];            // [128 n][128 j]
    {
        const int nl = t >> 1;
        const int cb = (t & 1) * 64;
        const float* src = X + ((size_t)nb2 * 128 + nl) * D1 + jc * 128 + cb;
        #pragma unroll
        for (int c = 0; c < 16; ++c) {
            float4 v = *reinterpret_cast<const float4*>(src + c * 4);
            *reinterpret_cast<float4*>(&xt[nl * 128 + cb + c * 4]) = v;
        }
    }
    __syncthreads();
    bf16_t* outx = Xbf + ((size_t)nb2 * 4 + jc) * 16384;
    #pragma unroll
    for (int p = 0; p < 8; ++p) {
        const int cc   = p * 256 + t;
        const int n    = cc >> 4;
        const int slot = cc & 15;
        const int j8   = slot ^ (n & 15);
        bf16x8 h;
        #pragma unroll
        for (int e = 0; e < 8; ++e) h[e] = (bf16_t)xt[n * 128 + j8 * 8 + e];
        *reinterpret_cast<bf16x8*>(outx + (size_t)cc * 8) = h;
    }
}

// ---------------- main: W-as-A, X-as-B. Block = (k, 128-row n-tile), 16 waves (1024 thr).
// Wave = R9's exact 64i x 64n structure (acc[2][2]=64 AGPR, Aq[2][2], B ping-pong),
// with all 16-wave-specific offsets hoisted into base pointers (sbase absorbs the
// n-half, myred the red slot) so loop address math is byte-identical to R9.
// BN=128 => per XCD round ONE W_k (512 KB, L2-hot) serves 32 CUs: per-CU A-demand
// ~16 B/cyc (was 63 ~= the per-CU L2 ceiling). 1 block/CU, 4 waves/SIMD, 132 KB LDS.
__global__ __launch_bounds__(1024, 4)
void tr_main(const bf16_t* __restrict__ Wbf, const bf16_t* __restrict__ Xbf,
             float* __restrict__ Y)
{
    extern __shared__ char smem[];         // 4 x 32 KB X tiles + 4 KB red
    float* red = (float*)(smem + 131072);

    const int bid = blockIdx.x;
    const int k   = (bid & 7) + 8 * (bid >> 8);   // per XCD round: ONE hot W_k
    const int nt  = (bid >> 3) & 31;              // 128-row n-tile (image nb2 slot)

    const int tid = threadIdx.x;
    const int w   = tid >> 6;              // 0..15
    const int is  = w >> 1;                // i-strip 0..7
    const int h   = w & 1;                 // n-half 0..1
    const int l   = tid & 63;
    const int l31 = l & 31;
    const int lh  = l >> 5;
    const int sw  = (l & 15) << 4;

    // stage all 4 X jc-tiles (128 KB), two half-passes of tmp[4] (low reg peak)
    {
        const bf16_t* src = Xbf + (size_t)nt * 65536;
        #pragma unroll
        for (int g = 0; g < 2; ++g) {
            bf16x8 tmp[4];
            #pragma unroll
            for (int jc = 0; jc < 2; ++jc)
                #pragma unroll
                for (int p = 0; p < 2; ++p) {
                    const int ci = p * 1024 + tid;   // 0..2047
                    tmp[jc * 2 + p] = *reinterpret_cast<const bf16x8*>(
                        src + (size_t)(g * 2 + jc) * 16384 + (size_t)ci * 8);
                }
            #pragma unroll
            for (int jc = 0; jc < 2; ++jc)
                #pragma unroll
                for (int p = 0; p < 2; ++p) {
                    const int ci = p * 1024 + tid;
                    *reinterpret_cast<bf16x8*>(smem + (g * 2 + jc) * 32768 + ci * 16) =
                        tmp[jc * 2 + p];
                }
        }
    }
    __syncthreads();

    // per-thread base pointers (hoisted; keep loop math identical to R9)
    const char* sbase = smem + h * 16384;  // absorbs n-half row offset
    const bf16_t* A0 = Wbf + ((size_t)k * 16 + is * 2) * 16384 + (size_t)l * 8;

    f32x16 acc[2][2] = {};

    // depth-2 A-prefetch queue (statically indexed under full unroll)
    bf16x8 Aq[2][2];
    #pragma unroll
    for (int d = 0; d < 2; ++d) {
        Aq[d][0] = *reinterpret_cast<const bf16x8*>(A0 + (size_t)d * 512);
        Aq[d][1] = *reinterpret_cast<const bf16x8*>(A0 + 16384 + (size_t)d * 512);
    }

    auto bread = [&](bf16x8* dst, int su) { // su = j-chunk index 0..31
        const char* base = sbase + (su >> 3) * 32768;
        const int ct = ((((su & 7) * 2 + lh) << 4)) ^ sw;
        #pragma unroll
        for (int fn = 0; fn < 2; ++fn)
            dst[fn] = *reinterpret_cast<const bf16x8*>(
                base + (fn * 32 + l31) * 256 + ct);
    };

    // B ping-pong: reads for step s+1 issue before step s's MFMA burst (R9 form)
    bf16x8 B[2][2];
    bread(B[0], 0);

    #pragma unroll
    for (int s = 0; s < 32; ++s) {
        const int qi = s & 1;
        bf16x8 a0 = Aq[qi][0];
        bf16x8 a1 = Aq[qi][1];
        if (s + 2 < 32) {                  // A prefetch, 2 steps ahead (L2-resident)
            Aq[qi][0] = *reinterpret_cast<const bf16x8*>(A0 + (size_t)(s + 2) * 512);
            Aq[qi][1] = *reinterpret_cast<const bf16x8*>(A0 + 16384 + (size_t)(s + 2) * 512);
        }
        if (s < 31) bread(B[(s + 1) & 1], s + 1);   // B prefetch, 1 step ahead
        __builtin_amdgcn_s_setprio(1);
        acc[0][0] = __builtin_amdgcn_mfma_f32_32x32x16_bf16(a0, B[qi][0], acc[0][0], 0, 0, 0);
        acc[0][1] = __builtin_amdgcn_mfma_f32_32x32x16_bf16(a0, B[qi][1], acc[0][1], 0, 0, 0);
        acc[1][0] = __builtin_amdgcn_mfma_f32_32x32x16_bf16(a1, B[qi][0], acc[1][0], 0, 0, 0);
        acc[1][1] = __builtin_amdgcn_mfma_f32_32x32x16_bf16(a1, B[qi][1], acc[1][1], 0, 0, 0);
        __builtin_amdgcn_s_setprio(0);
    }

    // fold: yp[n] = sum_i acc[i,n] * X[n,i], X from the resident LDS tiles.
    // C/D: col(n)=l&31, row(i)=st32*32+(r&3)+8*(r>>2)+4*lh; i-quads 4-consecutive.
    // sbase absorbs h: row-in-tile = h*64 + (fn*32+l31); (n&15) == ((fn*32+l31)&15).
    float yp[2] = {0.f, 0.f};
    #pragma unroll
    for (int mi = 0; mi < 2; ++mi) {
        const int st32 = is * 2 + mi;
        const char* base = sbase + (st32 >> 2) * 32768;
        #pragma unroll
        for (int rq = 0; rq < 4; ++rq) {
            const int slot = (st32 * 4 + rq) & 15;
            #pragma unroll
            for (int fn = 0; fn < 2; ++fn) {
                const int nn = fn * 32 + l31;
                bf16x4 xv = *reinterpret_cast<const bf16x4*>(
                    base + nn * 256 + ((slot ^ (nn & 15)) << 4) + lh * 8);
                #pragma unroll
                for (int q = 0; q < 4; ++q)
                    yp[fn] += acc[mi][fn][rq * 4 + q] * (float)xv[q];
            }
        }
    }
    {
        float* myred = red + is * 128 + h * 64;
        #pragma unroll
        for (int fn = 0; fn < 2; ++fn) {
            float v = yp[fn];
            v += __shfl_down(v, 32);
            if (lh == 0) myred[fn * 32 + l31] = v;   // unique slot per (is,h,fn,l31)
        }
    }
    __syncthreads();
    if (tid < 128) {
        float s2 = 0.f;
        #pragma unroll
        for (int i2 = 0; i2 < 8; ++i2) s2 += red[i2 * 128 + tid];
        Y[((size_t)nt * 128 + tid) * K2 + k] = s2;
    }
}

// ---------------- fallback (R1, proven 458 us, no ws) ----------------
__global__ __launch_bounds__(512, 2)
void tensor_reduction_kernel(const float* __restrict__ X,
                             const float* __restrict__ W,
                             float* __restrict__ Y)
{
    const int bid = blockIdx.x;
    const int xcd = bid & 7;
    const int rr_ = bid >> 3;
    const int kk  = xcd + 8 * (rr_ >> 4);
    const int nb  = (rr_ & 15) * 256;

    const int tid = threadIdx.x;
    const int wv  = tid >> 6;
    const int ln  = tid & 63;
    const int lg  = ln >> 4;
    const int lr  = ln & 15;

    __shared__ __align__(16) bf16_t Xs[256 * 64];
    __shared__ __align__(16) bf16_t Ws[2][64 * 64];

    bf16x8 afrag[2][16];
    {
        const int srow = tid >> 4;
        const int sj4  = (tid & 15) * 4;
        #pragma unroll
        for (int c = 0; c < 8; ++c) {
            #pragma unroll
            for (int p = 0; p < 8; ++p) {
                const int row = p * 32 + srow;
                float4 v = *reinterpret_cast<const float4*>(
                    X + (size_t)(nb + row) * D1 + c * 64 + sj4);
                bf16x4 h = { (bf16_t)v.x, (bf16_t)v.y, (bf16_t)v.z, (bf16_t)v.w };
                const int byte = row * 128 + ((sj4 * 2) ^ ((row & 7) << 4));
                *reinterpret_cast<bf16x4*>((char*)Xs + byte) = h;
            }
            __syncthreads();
            #pragma unroll
            for (int m = 0; m < 2; ++m) {
                #pragma unroll
                for (int ks = 0; ks < 2; ++ks) {
                    const int row  = wv * 32 + m * 16 + lr;
                    const int byte = row * 128 + ((ks * 64 + lg * 16) ^ ((row & 7) << 4));
                    afrag[m][2 * c + ks] =
                        *reinterpret_cast<const bf16x8*>((const char*)Xs + byte);
                }
            }
            __syncthreads();
        }
    }

    const float* Wk  = W + (size_t)kk * D1 * D1;
    const int irow = tid >> 3;
    const int j8   = (tid & 7) * 8;

    float ypart[2][4] = {{0.f,0.f,0.f,0.f},{0.f,0.f,0.f,0.f}};

    {
        const float* src = Wk + (size_t)irow * D1 + j8;
        float4 u0 = *reinterpret_cast<const float4*>(src);
        float4 u1 = *reinterpret_cast<const float4*>(src + 4);
        bf16x8 h = { (bf16_t)u0.x,(bf16_t)u0.y,(bf16_t)u0.z,(bf16_t)u0.w,
                     (bf16_t)u1.x,(bf16_t)u1.y,(bf16_t)u1.z,(bf16_t)u1.w };
        const int byte = irow * 128 + ((j8 * 2) ^ ((irow & 7) << 4));
        *reinterpret_cast<bf16x8*>((char*)Ws[0] + byte) = h;
    }
    __syncthreads();

    for (int it = 0; it < 8; ++it) {
        f32x4 acc[2][4] = {};
        #pragma unroll
        for (int jcc = 0; jcc < 8; ++jcc) {
            const int tI  = it * 8 + jcc;
            const int cur = tI & 1;
            float4 u0, u1;
            const bool pf = (tI < 63);
            if (pf) {
                const int nit = (tI + 1) >> 3, njc = (tI + 1) & 7;
                const float* src = Wk + (size_t)(nit * 64 + irow) * D1 + njc * 64 + j8;
                u0 = *reinterpret_cast<const float4*>(src);
                u1 = *reinterpret_cast<const float4*>(src + 4);
            }
            #pragma unroll
            for (int ks = 0; ks < 2; ++ks) {
                bf16x8 bfr[4];
                #pragma unroll
                for (int f = 0; f < 4; ++f) {
                    const int ir   = f * 16 + lr;
                    const int byte = ir * 128 + ((ks * 64 + lg * 16) ^ ((ir & 7) << 4));
                    bfr[f] = *reinterpret_cast<const bf16x8*>((const char*)Ws[cur] + byte);
                }
                #pragma unroll
                for (int m = 0; m < 2; ++m)
                    #pragma unroll
                    for (int f = 0; f < 4; ++f)
                        acc[m][f] = __builtin_amdgcn_mfma_f32_16x16x32_bf16(
                            afrag[m][2 * jcc + ks], bfr[f], acc[m][f], 0, 0, 0);
            }
            if (pf) {
                bf16x8 h = { (bf16_t)u0.x,(bf16_t)u0.y,(bf16_t)u0.z,(bf16_t)u0.w,
                             (bf16_t)u1.x,(bf16_t)u1.y,(bf16_t)u1.z,(bf16_t)u1.w };
                const int byte = irow * 128 + ((j8 * 2) ^ ((irow & 7) << 4));
                *reinterpret_cast<bf16x8*>((char*)Ws[cur ^ 1] + byte) = h;
            }
            __syncthreads();
        }
        #pragma unroll
        for (int m = 0; m < 2; ++m) {
            #pragma unroll
            for (int f = 0; f < 4; ++f) {
                const int col = it * 64 + f * 16 + lr;
                #pragma unroll
                for (int q = 0; q < 4; ++q) {
                    const int grow = nb + wv * 32 + m * 16 + lg * 4 + q;
                    ypart[m][q] += acc[m][f][q] * X[(size_t)grow * D1 + col];
                }
            }
        }
    }

    #pragma unroll
    for (int m = 0; m < 2; ++m) {
        #pragma unroll
        for (int q = 0; q < 4; ++q) {
            float v = ypart[m][q];
            v += __shfl_xor(v, 1, 64);
            v += __shfl_xor(v, 2, 64);
            v += __shfl_xor(v, 4, 64);
            v += __shfl_xor(v, 8, 64);
            if (lr == 0) {
                const int grow = nb + wv * 32 + m * 16 + lg * 4 + q;
                Y[(size_t)grow * K2 + kk] = v;
            }
        }
    }
}

extern "C" void kernel_launch(void* const* d_in, const int* in_sizes, int n_in,
                              void* d_out, int out_size, void* d_ws, size_t ws_size,
                              hipStream_t stream)
{
    const float* X = (const float*)d_in[0];   // [4096, 512] fp32
    const float* W = (const float*)d_in[1];   // [128, 512, 512] fp32
    float* Y = (float*)d_out;                 // [4096, 128] fp32

    if (d_ws != nullptr && ws_size >= WS_NEED) {
        bf16_t* Wbf = (bf16_t*)((char*)d_ws + WBF_OFF);
        bf16_t* Xbf = (bf16_t*)((char*)d_ws + XBF_OFF);
        prep_w<<<2048, 256, 0, stream>>>(W, Wbf);
        prep_x<<<128, 256, 0, stream>>>(X, Xbf);
        (void)hipFuncSetAttribute((const void*)tr_main,
                                  hipFuncAttributeMaxDynamicSharedMemorySize, 135168);
        tr_main<<<4096, 1024, 135168, stream>>>(Wbf, Xbf, Y);
    } else {
        tensor_reduction_kernel<<<2048, 512, 0, stream>>>(X, W, Y);
    }
}

// Round 17
// 278.248 us; speedup vs baseline: 1.3777x; 1.1851x over previous
//
#include <hip/hip_runtime.h>

#define D1 512
#define K2 128

typedef __bf16 bf16_t;
typedef bf16_t bf16x8 __attribute__((ext_vector_type(8)));
typedef bf16_t bf16x4 __attribute__((ext_vector_type(4)));
typedef float  f32x4  __attribute__((ext_vector_type(4)));
typedef float  f32x16 __attribute__((ext_vector_type(16)));

#define WBF_OFF 0ull
#define XBF_OFF 67108864ull
#define WS_NEED 71303168ull

// ---------------- prep W: fp32 [k][i][j] -> Wbf bf16 A-frag stream ----------------
// Wbf[k][is(16)][s(32)][l(64)][e(8)]: lane l of a wave loads 16B = W[k][is*32+(l&31)][s*16+(l>>5)*8+e]
__global__ __launch_bounds__(256)
void prep_w(const float* __restrict__ W, bf16_t* __restrict__ Wbf)
{
    const int k  = blockIdx.x >> 4;
    const int is = blockIdx.x & 15;
    const int t  = threadIdx.x;
    __shared__ float lt[16384];            // 32 rows x 2048 B, 16B-slot XOR swizzle
    char* ltb = (char*)lt;
    {
        const int r  = t >> 3;
        const int cb = (t & 7) * 64;
        const float* src = W + ((size_t)k * D1 + is * 32 + r) * D1 + cb;
        const int sw = (r & 15) << 4;
        #pragma unroll
        for (int c = 0; c < 16; ++c) {
            float4 v = *reinterpret_cast<const float4*>(src + c * 4);
            *reinterpret_cast<float4*>(ltb + r * 2048 + (((cb + c * 4) * 4) ^ sw)) = v;
        }
    }
    __syncthreads();
    bf16_t* out = Wbf + ((size_t)k * 16 + is) * 16384;
    #pragma unroll
    for (int p = 0; p < 8; ++p) {
        const int cc = p * 256 + t;        // 0..2047 = s*64 + l
        const int s  = cc >> 6;
        const int l2 = cc & 63;
        const int il = l2 & 31;
        const int jb = s * 16 + (l2 >> 5) * 8;
        const int sw = (il & 15) << 4;
        bf16x8 h;
        #pragma unroll
        for (int e = 0; e < 8; ++e) {
            float v = *reinterpret_cast<const float*>(ltb + il * 2048 + (((jb + e) * 4) ^ sw));
            h[e] = (bf16_t)v;
        }
        *reinterpret_cast<bf16x8*>(out + (size_t)cc * 8) = h;
    }
}

// ---------------- prep X: fp32 [n][d] -> Xbf (B-frag LDS image, pre-swizzled)
// Xbf[nb2(32)][jc(4)][chunk(2048)][e(8)]: chunk = n*16+slot, content = X[nb2*128+n][jc*128+(slot^(n&15))*8+e]
__global__ __launch_bounds__(256)
void prep_x(const float* __restrict__ X, bf16_t* __restrict__ Xbf)
{
    const int nb2 = blockIdx.x >> 2;
    const int jc  = blockIdx.x & 3;
    const int t   = threadIdx.x;
    __shared__ float xt[16384];            // [128 n][128 j]
    {
        const int nl = t >> 1;
        const int cb = (t & 1) * 64;
        const float* src = X + ((size_t)nb2 * 128 + nl) * D1 + jc * 128 + cb;
        #pragma unroll
        for (int c = 0; c < 16; ++c) {
            float4 v = *reinterpret_cast<const float4*>(src + c * 4);
            *reinterpret_cast<float4*>(&xt[nl * 128 + cb + c * 4]) = v;
        }
    }
    __syncthreads();
    bf16_t* outx = Xbf + ((size_t)nb2 * 4 + jc) * 16384;
    #pragma unroll
    for (int p = 0; p < 8; ++p) {
        const int cc   = p * 256 + t;
        const int n    = cc >> 4;
        const int slot = cc & 15;
        const int j8   = slot ^ (n & 15);
        bf16x8 h;
        #pragma unroll
        for (int e = 0; e < 8; ++e) h[e] = (bf16_t)xt[n * 128 + j8 * 8 + e];
        *reinterpret_cast<bf16x8*>(outx + (size_t)cc * 8) = h;
    }
}

// ---------------- main: W-as-A, X-as-B. Block = (k, 64-row n-tile), 8 waves.
// Proven best (R13, 240 us main / 278 us total, MfmaUtil 55%, 0 spill):
// wave = 64i x 64n, acc[2][2] = 64 AGPR, 4 waves/SIMD, 2 blocks/CU, 66 KB LDS.
// B double-buffer 2-step-ahead (refill just-consumed slot after the burst,
// sched_barrier-pinned); A depth-2 queue from L2-hot Wbf; setprio on the burst.
__global__ __launch_bounds__(512, 4)
void tr_main(const bf16_t* __restrict__ Wbf, const bf16_t* __restrict__ Xbf,
             float* __restrict__ Y)
{
    extern __shared__ char smem[];         // 4 x 16 KB X half-tiles + 2 KB reduce
    float* red = (float*)(smem + 65536);

    const int bid = blockIdx.x;
    const int k   = (bid & 7) + ((bid >> 9) << 3);  // same-k blocks share an XCD
    const int nb  = (bid >> 3) & 63;                // 64-row n-tile

    const int tid = threadIdx.x;
    const int w   = tid >> 6;
    const int l   = tid & 63;
    const int l31 = l & 31;
    const int lh  = l >> 5;

    // stage 4 X half-tiles (16 KB each) from the pre-swizzled image, reg-staged
    {
        const bf16_t* src = Xbf + (size_t)(nb >> 1) * 65536 + (size_t)(nb & 1) * 8192;
        bf16x8 tmp[8];
        #pragma unroll
        for (int jc = 0; jc < 4; ++jc)
            #pragma unroll
            for (int p = 0; p < 2; ++p) {
                const int ci = p * 512 + tid;        // 0..1023
                tmp[jc * 2 + p] = *reinterpret_cast<const bf16x8*>(
                    src + (size_t)jc * 16384 + (size_t)ci * 8);
            }
        #pragma unroll
        for (int jc = 0; jc < 4; ++jc)
            #pragma unroll
            for (int p = 0; p < 2; ++p) {
                const int ci = p * 512 + tid;
                *reinterpret_cast<bf16x8*>(smem + jc * 16384 + ci * 16) = tmp[jc * 2 + p];
            }
    }
    __syncthreads();

    // A-frag stream: strip mi at A0 + mi*16384 (wave w owns i in [w*64, w*64+64))
    const bf16_t* A0 = Wbf + ((size_t)k * 16 + w * 2) * 16384 + (size_t)l * 8;
    const int sw = (l & 15) << 4;

    f32x16 acc[2][2] = {};

    // depth-2 A-prefetch queue (statically indexed under full unroll)
    bf16x8 Aq[2][2];
    #pragma unroll
    for (int d = 0; d < 2; ++d) {
        Aq[d][0] = *reinterpret_cast<const bf16x8*>(A0 + (size_t)d * 512);
        Aq[d][1] = *reinterpret_cast<const bf16x8*>(A0 + 16384 + (size_t)d * 512);
    }

    auto bread = [&](bf16x8* dst, int su) { // su = j-chunk index 0..31
        const char* base = smem + (su >> 3) * 16384;
        const int ct = ((((su & 7) * 2 + lh) << 4)) ^ sw;
        #pragma unroll
        for (int fn = 0; fn < 2; ++fn)
            dst[fn] = *reinterpret_cast<const bf16x8*>(
                base + (fn * 32 + l31) * 256 + ct);
    };

    // B double-buffer, 2-step-ahead: slot qi is refilled for s+2 right after
    // step s's burst consumes it. Prologue fills steps 0 and 1.
    bf16x8 B[2][2];
    bread(B[0], 0);
    bread(B[1], 1);

    #pragma unroll
    for (int s = 0; s < 32; ++s) {
        const int qi = s & 1;
        bf16x8 a0 = Aq[qi][0];
        bf16x8 a1 = Aq[qi][1];
        if (s + 2 < 32) {                  // A prefetch, 2 steps ahead (L2-resident)
            Aq[qi][0] = *reinterpret_cast<const bf16x8*>(A0 + (size_t)(s + 2) * 512);
            Aq[qi][1] = *reinterpret_cast<const bf16x8*>(A0 + 16384 + (size_t)(s + 2) * 512);
        }
        __builtin_amdgcn_s_setprio(1);
        acc[0][0] = __builtin_amdgcn_mfma_f32_32x32x16_bf16(a0, B[qi][0], acc[0][0], 0, 0, 0);
        acc[0][1] = __builtin_amdgcn_mfma_f32_32x32x16_bf16(a0, B[qi][1], acc[0][1], 0, 0, 0);
        acc[1][0] = __builtin_amdgcn_mfma_f32_32x32x16_bf16(a1, B[qi][0], acc[1][0], 0, 0, 0);
        acc[1][1] = __builtin_amdgcn_mfma_f32_32x32x16_bf16(a1, B[qi][1], acc[1][1], 0, 0, 0);
        __builtin_amdgcn_s_setprio(0);
        __builtin_amdgcn_sched_barrier(0);  // pin the refill BELOW the burst
        if (s + 2 < 32) bread(B[qi], s + 2);   // refill consumed slot, 2 ahead
    }

    // epilogue: yp[n] = sum_i acc[i,n] * X[n,i], X from the resident LDS tiles.
    // C/D: col(n)=l&31, row(i)=st32*32+(r&3)+8*(r>>2)+4*lh; i-quads 4-consecutive.
    float yp[2] = {0.f, 0.f};
    #pragma unroll
    for (int mi = 0; mi < 2; ++mi) {
        const int st32 = w * 2 + mi;
        const char* base = smem + (st32 >> 2) * 16384;
        #pragma unroll
        for (int rq = 0; rq < 4; ++rq) {
            const int slot = (st32 * 4 + rq) & 15;
            #pragma unroll
            for (int fn = 0; fn < 2; ++fn) {
                const int n = fn * 32 + l31;
                bf16x4 xv = *reinterpret_cast<const bf16x4*>(
                    base + n * 256 + ((slot ^ (n & 15)) << 4) + lh * 8);
                #pragma unroll
                for (int q = 0; q < 4; ++q)
                    yp[fn] += acc[mi][fn][rq * 4 + q] * (float)xv[q];
            }
        }
    }
    #pragma unroll
    for (int fn = 0; fn < 2; ++fn) {
        float v = yp[fn];
        v += __shfl_down(v, 32);
        if (lh == 0) red[w * 64 + fn * 32 + l31] = v;
    }
    __syncthreads();
    if (tid < 64) {
        float s2 = 0.f;
        #pragma unroll
        for (int w2 = 0; w2 < 8; ++w2) s2 += red[w2 * 64 + tid];
        Y[((size_t)nb * 64 + tid) * K2 + k] = s2;
    }
}

// ---------------- fallback (R1, proven 458 us, no ws) ----------------
__global__ __launch_bounds__(512, 2)
void tensor_reduction_kernel(const float* __restrict__ X,
                             const float* __restrict__ W,
                             float* __restrict__ Y)
{
    const int bid = blockIdx.x;
    const int xcd = bid & 7;
    const int rr_ = bid >> 3;
    const int kk  = xcd + 8 * (rr_ >> 4);
    const int nb  = (rr_ & 15) * 256;

    const int tid = threadIdx.x;
    const int wv  = tid >> 6;
    const int ln  = tid & 63;
    const int lg  = ln >> 4;
    const int lr  = ln & 15;

    __shared__ __align__(16) bf16_t Xs[256 * 64];
    __shared__ __align__(16) bf16_t Ws[2][64 * 64];

    bf16x8 afrag[2][16];
    {
        const int srow = tid >> 4;
        const int sj4  = (tid & 15) * 4;
        #pragma unroll
        for (int c = 0; c < 8; ++c) {
            #pragma unroll
            for (int p = 0; p < 8; ++p) {
                const int row = p * 32 + srow;
                float4 v = *reinterpret_cast<const float4*>(
                    X + (size_t)(nb + row) * D1 + c * 64 + sj4);
                bf16x4 h = { (bf16_t)v.x, (bf16_t)v.y, (bf16_t)v.z, (bf16_t)v.w };
                const int byte = row * 128 + ((sj4 * 2) ^ ((row & 7) << 4));
                *reinterpret_cast<bf16x4*>((char*)Xs + byte) = h;
            }
            __syncthreads();
            #pragma unroll
            for (int m = 0; m < 2; ++m) {
                #pragma unroll
                for (int ks = 0; ks < 2; ++ks) {
                    const int row  = wv * 32 + m * 16 + lr;
                    const int byte = row * 128 + ((ks * 64 + lg * 16) ^ ((row & 7) << 4));
                    afrag[m][2 * c + ks] =
                        *reinterpret_cast<const bf16x8*>((const char*)Xs + byte);
                }
            }
            __syncthreads();
        }
    }

    const float* Wk  = W + (size_t)kk * D1 * D1;
    const int irow = tid >> 3;
    const int j8   = (tid & 7) * 8;

    float ypart[2][4] = {{0.f,0.f,0.f,0.f},{0.f,0.f,0.f,0.f}};

    {
        const float* src = Wk + (size_t)irow * D1 + j8;
        float4 u0 = *reinterpret_cast<const float4*>(src);
        float4 u1 = *reinterpret_cast<const float4*>(src + 4);
        bf16x8 h = { (bf16_t)u0.x,(bf16_t)u0.y,(bf16_t)u0.z,(bf16_t)u0.w,
                     (bf16_t)u1.x,(bf16_t)u1.y,(bf16_t)u1.z,(bf16_t)u1.w };
        const int byte = irow * 128 + ((j8 * 2) ^ ((irow & 7) << 4));
        *reinterpret_cast<bf16x8*>((char*)Ws[0] + byte) = h;
    }
    __syncthreads();

    for (int it = 0; it < 8; ++it) {
        f32x4 acc[2][4] = {};
        #pragma unroll
        for (int jcc = 0; jcc < 8; ++jcc) {
            const int tI  = it * 8 + jcc;
            const int cur = tI & 1;
            float4 u0, u1;
            const bool pf = (tI < 63);
            if (pf) {
                const int nit = (tI + 1) >> 3, njc = (tI + 1) & 7;
                const float* src = Wk + (size_t)(nit * 64 + irow) * D1 + njc * 64 + j8;
                u0 = *reinterpret_cast<const float4*>(src);
                u1 = *reinterpret_cast<const float4*>(src + 4);
            }
            #pragma unroll
            for (int ks = 0; ks < 2; ++ks) {
                bf16x8 bfr[4];
                #pragma unroll
                for (int f = 0; f < 4; ++f) {
                    const int ir   = f * 16 + lr;
                    const int byte = ir * 128 + ((ks * 64 + lg * 16) ^ ((ir & 7) << 4));
                    bfr[f] = *reinterpret_cast<const bf16x8*>((const char*)Ws[cur] + byte);
                }
                #pragma unroll
                for (int m = 0; m < 2; ++m)
                    #pragma unroll
                    for (int f = 0; f < 4; ++f)
                        acc[m][f] = __builtin_amdgcn_mfma_f32_16x16x32_bf16(
                            afrag[m][2 * jcc + ks], bfr[f], acc[m][f], 0, 0, 0);
            }
            if (pf) {
                bf16x8 h = { (bf16_t)u0.x,(bf16_t)u0.y,(bf16_t)u0.z,(bf16_t)u0.w,
                             (bf16_t)u1.x,(bf16_t)u1.y,(bf16_t)u1.z,(bf16_t)u1.w };
                const int byte = irow * 128 + ((j8 * 2) ^ ((irow & 7) << 4));
                *reinterpret_cast<bf16x8*>((char*)Ws[cur ^ 1] + byte) = h;
            }
            __syncthreads();
        }
        #pragma unroll
        for (int m = 0; m < 2; ++m) {
            #pragma unroll
            for (int f = 0; f < 4; ++f) {
                const int col = it * 64 + f * 16 + lr;
                #pragma unroll
                for (int q = 0; q < 4; ++q) {
                    const int grow = nb + wv * 32 + m * 16 + lg * 4 + q;
                    ypart[m][q] += acc[m][f][q] * X[(size_t)grow * D1 + col];
                }
            }
        }
    }

    #pragma unroll
    for (int m = 0; m < 2; ++m) {
        #pragma unroll
        for (int q = 0; q < 4; ++q) {
            float v = ypart[m][q];
            v += __shfl_xor(v, 1, 64);
            v += __shfl_xor(v, 2, 64);
            v += __shfl_xor(v, 4, 64);
            v += __shfl_xor(v, 8, 64);
            if (lr == 0) {
                const int grow = nb + wv * 32 + m * 16 + lg * 4 + q;
                Y[(size_t)grow * K2 + kk] = v;
            }
        }
    }
}

extern "C" void kernel_launch(void* const* d_in, const int* in_sizes, int n_in,
                              void* d_out, int out_size, void* d_ws, size_t ws_size,
                              hipStream_t stream)
{
    const float* X = (const float*)d_in[0];   // [4096, 512] fp32
    const float* W = (const float*)d_in[1];   // [128, 512, 512] fp32
    float* Y = (float*)d_out;                 // [4096, 128] fp32

    if (d_ws != nullptr && ws_size >= WS_NEED) {
        bf16_t* Wbf = (bf16_t*)((char*)d_ws + WBF_OFF);
        bf16_t* Xbf = (bf16_t*)((char*)d_ws + XBF_OFF);
        prep_w<<<2048, 256, 0, stream>>>(W, Wbf);
        prep_x<<<128, 256, 0, stream>>>(X, Xbf);
        (void)hipFuncSetAttribute((const void*)tr_main,
                                  hipFuncAttributeMaxDynamicSharedMemorySize, 67584);
        tr_main<<<8192, 512, 67584, stream>>>(Wbf, Xbf, Y);
    } else {
        tensor_reduction_kernel<<<2048, 512, 0, stream>>>(X, W, Y);
    }
}